// Round 3
// baseline (1589.966 us; speedup 1.0000x reference)
//
#include <hip/hip_runtime.h>

typedef _Float16 f16;
typedef _Float16 f16x8 __attribute__((ext_vector_type(8)));
typedef float f32x4 __attribute__((ext_vector_type(4)));

#define LN4 1.3862943611198906f

__device__ __forceinline__ void gl_lds16(const void* g, void* l) {
    typedef unsigned int u32;
    __builtin_amdgcn_global_load_lds(
        (const __attribute__((address_space(1))) u32*)(g),
        (__attribute__((address_space(3))) u32*)(l), 16, 0, 0);
}

// ===========================================================================
// Weight prep: fp32 W[27][CIN][CIN] -> f16 hi/lo transposed:
// WT[d][tap][ h(CIN) | l(CIN) ], d<CIN, tap<28 (tap 27 = zeros).
// ===========================================================================
template<int CIN>
__global__ __launch_bounds__(256) void prep_wt(
    const float* __restrict__ W, f16* __restrict__ dst)
{
    const int RE = 2 * CIN;
    int total = CIN * 28 * CIN;
    for (int i = blockIdx.x * 256 + threadIdx.x; i < total; i += gridDim.x * 256) {
        int d = i / (28 * CIN);
        int rem = i - d * (28 * CIN);
        int tap = rem / CIN;
        int c = rem - tap * CIN;
        float v = (tap < 27) ? W[(size_t)(tap * CIN + c) * CIN + d] : 0.f;
        f16 h = (f16)v;
        size_t base = (size_t)d * (28 * RE) + (size_t)tap * RE;
        dst[base + c] = h;
        dst[base + CIN + c] = (f16)(v - (float)h);
    }
}

// ===========================================================================
// Score-weight fragment table for score_tile's B operand.
// Layout: FT[(p*KB+kb)][term(2)][lane(64)][8] f16  (1024 f16 per (p,kb)).
// Element: k = kb*32 + (lane>>4)*8 + j; ts=k>=CIN; kk=k-ts*CIN; tap=2p+ts;
// col=lane&15. Weight cols concatenated from (Wa,ca)|(Wb,cb)|(Wc,cc).
// ===========================================================================
template<int CIN, int COUT>
__global__ __launch_bounds__(256) void prep_frag(
    const float* __restrict__ Wa, int ca,
    const float* __restrict__ Wb, int cb,
    const float* __restrict__ Wc, int cc,
    f16* __restrict__ FT)
{
    constexpr int KB = (2 * CIN) / 32;
    int total = 14 * KB * 1024;
    for (int i = blockIdx.x * 256 + threadIdx.x; i < total; i += gridDim.x * 256) {
        int j = i & 7;
        int lane = (i >> 3) & 63;
        int term = (i >> 9) & 1;
        int kbp = i >> 10;
        int kb = kbp % KB, p = kbp / KB;
        int k = kb * 32 + ((lane >> 4) * 8) + j;
        int ts = (k >= CIN) ? 1 : 0;
        int kk = k - ts * CIN;
        int tap = 2 * p + ts;
        int col = lane & 15;
        float v = 0.f;
        if (tap < 27 && col < COUT) {
            int kc = tap * CIN + kk;
            if (col < ca)            v = Wa[(size_t)kc * ca + col];
            else if (col < ca + cb)  v = Wb[(size_t)kc * cb + (col - ca)];
            else                     v = Wc[(size_t)kc * cc + (col - ca - cb)];
        }
        f16 h = (f16)v;
        FT[i] = term ? (f16)(v - (float)h) : h;
    }
}

// ===========================================================================
// Feature split (+optional gating): rows [h(CIN)|l(CIN)] f16, zero row at N.
// parent==nullptr -> no gate.
// ===========================================================================
template<int CIN>
__global__ __launch_bounds__(256) void split_gated(
    const float* __restrict__ f, const float* __restrict__ mask,
    const int* __restrict__ parent, f16* __restrict__ Fc, int N)
{
    int i = blockIdx.x * 256 + threadIdx.x;
    if (i >= (N + 1) * CIN) return;
    int n = i / CIN, c = i - n * CIN;
    float v = 0.f;
    if (n < N) {
        bool a = parent ? (mask[parent[n]] != 0.f) : true;
        v = a ? f[i] : 0.f;
    }
    f16 h = (f16)v;
    Fc[(size_t)n * (2 * CIN) + c] = h;
    Fc[(size_t)n * (2 * CIN) + CIN + c] = (f16)(v - (float)h);
}

__global__ __launch_bounds__(256) void ppn_finalize_kernel(
    const int* __restrict__ coords, const float* __restrict__ s,
    float* __restrict__ ppn, float* __restrict__ mask, int N)
{
    int n = blockIdx.x * 256 + threadIdx.x;
    if (n >= N) return;
    float s0 = s[(size_t)n * 2 + 0], s1 = s[(size_t)n * 2 + 1];
    ppn[(size_t)n * 6 + 0] = (float)coords[(size_t)n * 4 + 0];
    ppn[(size_t)n * 6 + 1] = (float)coords[(size_t)n * 4 + 1];
    ppn[(size_t)n * 6 + 2] = (float)coords[(size_t)n * 4 + 2];
    ppn[(size_t)n * 6 + 3] = (float)coords[(size_t)n * 4 + 3];
    ppn[(size_t)n * 6 + 4] = s0;
    ppn[(size_t)n * 6 + 5] = s1;
    mask[n] = (s1 - s0 > LN4) ? 1.0f : 0.0f;
}

// ===========================================================================
// Dense MFMA conv tile CIN->CIN (f16 hi/lo split, 3-term), BM=64 rows/block,
// phase p processes taps {2p, 2p+1} packed as K = 2*CIN (hi parts; lo via
// 3-term). Output written as split hi/lo f16 rows (coalesced, NO atomics).
// Generalization of the R5-measured conv80 structure.
// ===========================================================================
template<int CIN>
__global__ __launch_bounds__(256, 3) void conv_tile(
    const f16* __restrict__ F, const int* __restrict__ nbr,
    const f16* __restrict__ WT, f16* __restrict__ Y, int N, int nTiles)
{
    constexpr int RE = 2 * CIN;        // f16 per row (hi|lo)
    constexpr int KB = RE / 32;        // K chunks per phase
    constexpr int CT = CIN / 16;       // acc tiles over output cols
    constexpr int CPT = RE / 8;        // 16B chunks per tap row in BS
    constexpr int CPR = 2 * CPT;       // chunks per BS row (2 taps)
    constexpr int PB = CPR * 16;       // BS row bytes
    __shared__ __align__(16) char BS[CIN * PB];

    const int t = threadIdx.x;
    const int lane = t & 63;
    const int l16 = lane & 15;
    const int quad = lane >> 4;
    const int wv = t >> 6;

    int q8 = (nTiles + 7) >> 3;
    int tile = (blockIdx.x & 7) * q8 + (blockIdx.x >> 3);
    if (tile >= nTiles) return;
    const int m0 = tile * 64;
    const int grow = m0 + wv * 16 + l16;

    f16x8 ah[2][KB], al[2][KB];

    auto loadA = [&](int p, int buf) {
        int i0 = N, i1 = N;
        if (grow < N) {
            i0 = nbr[(size_t)grow * 27 + 2 * p];
            if (2 * p + 1 < 27) i1 = nbr[(size_t)grow * 27 + 2 * p + 1];
        }
        #pragma unroll
        for (int kb = 0; kb < KB; ++kb) {
            int ko = kb * 32 + quad * 8;
            int ts = ko >= CIN;
            int c2 = ko - (ts ? CIN : 0);
            const f16* ap = F + (size_t)(ts ? i1 : i0) * RE + c2;
            ah[buf][kb] = *(const f16x8*)ap;
            al[buf][kb] = *(const f16x8*)(ap + CIN);
        }
    };

    auto stageB = [&](int p) {
        for (int i = t; i < CIN * CPR; i += 256) {
            int d = i / CPR, cs = i - d * CPR;
            int c = (cs & ~7) | ((cs ^ d) & 7);
            int tp = c / CPT, cc = c - tp * CPT;
            gl_lds16((const char*)WT + (((size_t)d * 28 + 2 * p + tp) * RE + cc * 8) * 2,
                     BS + (size_t)i * 16);
        }
    };

    f32x4 acc[CT];
    #pragma unroll
    for (int ct = 0; ct < CT; ++ct) acc[ct] = (f32x4){0.f, 0.f, 0.f, 0.f};

    auto compute = [&](int buf) {
        #pragma unroll
        for (int kb = 0; kb < KB; ++kb) {
            int ko = kb * 32 + quad * 8;
            int ts = ko >= CIN;
            int c2 = ko - (ts ? CIN : 0);
            int ch = ts * CPT + c2 / 8;
            int chl = ch + CIN / 8;
            #pragma unroll
            for (int ct = 0; ct < CT; ++ct) {
                int drow = ct * 16 + l16;
                int sb = (ch & ~7) | ((ch ^ drow) & 7);
                int sbl = (chl & ~7) | ((chl ^ drow) & 7);
                f16x8 bh = *(const f16x8*)(BS + drow * PB + sb * 16);
                f16x8 bl = *(const f16x8*)(BS + drow * PB + sbl * 16);
                acc[ct] = __builtin_amdgcn_mfma_f32_16x16x32_f16(ah[buf][kb], bh, acc[ct], 0, 0, 0);
                acc[ct] = __builtin_amdgcn_mfma_f32_16x16x32_f16(al[buf][kb], bh, acc[ct], 0, 0, 0);
                acc[ct] = __builtin_amdgcn_mfma_f32_16x16x32_f16(ah[buf][kb], bl, acc[ct], 0, 0, 0);
            }
        }
    };

    loadA(0, 0);
    #pragma unroll 1
    for (int p = 0; p < 14; ++p) {
        __syncthreads();
        stageB(p);
        if (p < 13) loadA(p + 1, (p + 1) & 1);
        __syncthreads();
        compute(p & 1);
    }

    // split-store epilogue (coalesced-ish 2B stores, no atomics)
    #pragma unroll
    for (int ct = 0; ct < CT; ++ct) {
        #pragma unroll
        for (int r = 0; r < 4; ++r) {
            int row = m0 + wv * 16 + quad * 4 + r;
            if (row < N) {
                int d = ct * 16 + l16;
                float v = acc[ct][r];
                f16 h = (f16)v;
                Y[(size_t)row * RE + d] = h;
                Y[(size_t)row * RE + CIN + d] = (f16)(v - (float)h);
            }
        }
    }
}

// ===========================================================================
// Gather-form score conv: S[n] = sum_t Y[nbr[n][t]] @ Ws[t], COUT<=16.
// MFMA tile, B operand from precomputed FT table (global, L2-hot). No LDS,
// no barriers, no atomics — each output row stored exactly once.
// ===========================================================================
template<int CIN, int COUT>
__global__ __launch_bounds__(256) void score_tile(
    const f16* __restrict__ Y, const int* __restrict__ nbr,
    const f16* __restrict__ FT, float* __restrict__ S, int N, int nTiles)
{
    constexpr int RE = 2 * CIN;
    constexpr int KB = RE / 32;

    const int t = threadIdx.x;
    const int lane = t & 63;
    const int l16 = lane & 15;
    const int quad = lane >> 4;
    const int wv = t >> 6;

    int q8 = (nTiles + 7) >> 3;
    int tile = (blockIdx.x & 7) * q8 + (blockIdx.x >> 3);
    if (tile >= nTiles) return;
    const int m0 = tile * 64;
    const int grow = m0 + wv * 16 + l16;
    const bool gv = grow < N;

    f32x4 acc = (f32x4){0.f, 0.f, 0.f, 0.f};

    #pragma unroll 1
    for (int p = 0; p < 14; ++p) {
        int i0 = N, i1 = N;
        if (gv) {
            i0 = nbr[(size_t)grow * 27 + 2 * p];
            if (2 * p + 1 < 27) i1 = nbr[(size_t)grow * 27 + 2 * p + 1];
        }
        #pragma unroll
        for (int kb = 0; kb < KB; ++kb) {
            int ko = kb * 32 + quad * 8;
            int ts = ko >= CIN;
            int c2 = ko - (ts ? CIN : 0);
            const f16* ap = Y + (size_t)(ts ? i1 : i0) * RE + c2;
            f16x8 ah = *(const f16x8*)ap;
            f16x8 al = *(const f16x8*)(ap + CIN);
            const f16* fb = FT + (size_t)(p * KB + kb) * 1024 + lane * 8;
            f16x8 bh = *(const f16x8*)fb;
            f16x8 bl = *(const f16x8*)(fb + 512);
            acc = __builtin_amdgcn_mfma_f32_16x16x32_f16(ah, bh, acc, 0, 0, 0);
            acc = __builtin_amdgcn_mfma_f32_16x16x32_f16(al, bh, acc, 0, 0, 0);
            acc = __builtin_amdgcn_mfma_f32_16x16x32_f16(ah, bl, acc, 0, 0, 0);
        }
    }

    if (l16 < COUT) {
        #pragma unroll
        for (int r = 0; r < 4; ++r) {
            int row = m0 + wv * 16 + quad * 4 + r;
            if (row < N) S[(size_t)row * COUT + l16] = acc[r];
        }
    }
}

// ===========================================================================
extern "C" void kernel_launch(void* const* d_in, const int* in_sizes, int n_in,
                              void* d_out, int out_size, void* d_ws, size_t ws_size,
                              hipStream_t stream)
{
    const float* feat1 = (const float*)d_in[0];
    const float* feat2 = (const float*)d_in[1];
    const float* feat3 = (const float*)d_in[2];
    const float* W1    = (const float*)d_in[3];
    const float* W1s   = (const float*)d_in[4];
    const float* W2    = (const float*)d_in[5];
    const float* W2s   = (const float*)d_in[6];
    const float* W3    = (const float*)d_in[7];
    const float* W3p   = (const float*)d_in[8];
    const float* W3s   = (const float*)d_in[9];
    const float* W3t   = (const float*)d_in[10];
    const int* nbr1    = (const int*)d_in[11];
    const int* nbr2    = (const int*)d_in[12];
    const int* nbr3    = (const int*)d_in[13];
    const int* parent2 = (const int*)d_in[14];
    const int* parent3 = (const int*)d_in[15];
    const int* coords1 = (const int*)d_in[16];
    const int* coords2 = (const int*)d_in[17];

    const int N1 = in_sizes[0] / 80;
    const int N2 = in_sizes[1] / 48;
    const int N3 = in_sizes[2] / 16;

    float* out = (float*)d_out;
    float* o_points = out;                              // [N3,10]
    float* o_ppn1   = o_points + (size_t)N3 * 10;       // [N1,6]
    float* o_ppn2   = o_ppn1 + (size_t)N1 * 6;          // [N2,6]
    float* o_mask1  = o_ppn2 + (size_t)N2 * 6;          // [N1]
    float* o_mask2  = o_mask1 + (size_t)N1;             // [N2]

    char* wp = (char*)d_ws;
    auto alloc = [&](size_t bytes) -> char* {
        char* r = wp; wp += (bytes + 255) & ~(size_t)255; return r;
    };

    f16* WT1 = (f16*)alloc((size_t)80 * 28 * 160 * 2);
    f16* WT2 = (f16*)alloc((size_t)48 * 28 * 96 * 2);
    f16* WT3 = (f16*)alloc((size_t)16 * 28 * 32 * 2);
    f16* FT1 = (f16*)alloc((size_t)14 * 5 * 1024 * 2);
    f16* FT2 = (f16*)alloc((size_t)14 * 3 * 1024 * 2);
    f16* FT3 = (f16*)alloc((size_t)14 * 1 * 1024 * 2);
    float* s1 = (float*)alloc((size_t)N1 * 2 * 4);
    float* s2 = (float*)alloc((size_t)N2 * 2 * 4);

    // two ping-pong f16 buffers reused across levels (max of per-level sizes)
    size_t e80 = (size_t)(N1 + 1) * 160;
    size_t e48 = (size_t)(N2 + 1) * 96;
    size_t e16 = (size_t)(N3 + 1) * 32;
    size_t emax = e80 > e48 ? e80 : e48; if (e16 > emax) emax = e16;
    f16* Fa = (f16*)alloc(emax * 2);   // gated split features
    f16* Yb = (f16*)alloc(emax * 2);   // conv outputs (split)

    auto cdiv = [](long long a, long long b) { return (int)((a + b - 1) / b); };

    // ---- weight prep (all independent) ----
    prep_wt<80><<<cdiv(80 * 28 * 80, 256), 256, 0, stream>>>(W1, WT1);
    prep_wt<48><<<cdiv(48 * 28 * 48, 256), 256, 0, stream>>>(W2, WT2);
    prep_wt<16><<<cdiv(16 * 28 * 16, 256), 256, 0, stream>>>(W3, WT3);
    prep_frag<80, 2><<<cdiv(14 * 5 * 1024, 256), 256, 0, stream>>>(
        W1s, 2, W1s, 0, W1s, 0, FT1);
    prep_frag<48, 2><<<cdiv(14 * 3 * 1024, 256), 256, 0, stream>>>(
        W2s, 2, W2s, 0, W2s, 0, FT2);
    prep_frag<16, 10><<<cdiv(14 * 1 * 1024, 256), 256, 0, stream>>>(
        W3p, 3, W3s, 2, W3t, 5, FT3);

    // ---- level 1 ----
    int T1 = cdiv(N1, 64);
    dim3 g1(8 * cdiv(T1, 8));
    split_gated<80><<<cdiv((size_t)(N1 + 1) * 80, 256), 256, 0, stream>>>(
        feat1, nullptr, nullptr, Fa, N1);
    conv_tile<80><<<g1, 256, 0, stream>>>(Fa, nbr1, WT1, Yb, N1, T1);
    hipMemsetAsync(Yb + (size_t)N1 * 160, 0, 160 * 2, stream);   // zero sentinel row
    score_tile<80, 2><<<g1, 256, 0, stream>>>(Yb, nbr1, FT1, s1, N1, T1);
    ppn_finalize_kernel<<<cdiv(N1, 256), 256, 0, stream>>>(coords1, s1, o_ppn1, o_mask1, N1);

    // ---- level 2 ----
    int T2 = cdiv(N2, 64);
    dim3 g2(8 * cdiv(T2, 8));
    split_gated<48><<<cdiv((size_t)(N2 + 1) * 48, 256), 256, 0, stream>>>(
        feat2, o_mask1, parent2, Fa, N2);
    conv_tile<48><<<g2, 256, 0, stream>>>(Fa, nbr2, WT2, Yb, N2, T2);
    hipMemsetAsync(Yb + (size_t)N2 * 96, 0, 96 * 2, stream);
    score_tile<48, 2><<<g2, 256, 0, stream>>>(Yb, nbr2, FT2, s2, N2, T2);
    ppn_finalize_kernel<<<cdiv(N2, 256), 256, 0, stream>>>(coords2, s2, o_ppn2, o_mask2, N2);

    // ---- level 3 ----
    int T3 = cdiv(N3, 64);
    dim3 g3(8 * cdiv(T3, 8));
    split_gated<16><<<cdiv((size_t)(N3 + 1) * 16, 256), 256, 0, stream>>>(
        feat3, o_mask2, parent3, Fa, N3);
    conv_tile<16><<<g3, 256, 0, stream>>>(Fa, nbr3, WT3, Yb, N3, T3);
    hipMemsetAsync(Yb + (size_t)N3 * 32, 0, 32 * 2, stream);
    score_tile<16, 10><<<g3, 256, 0, stream>>>(Yb, nbr3, FT3, o_points, N3, T3);
}

// Round 4
// 400.328 us; speedup vs baseline: 3.9717x; 3.9717x over previous
//
#include <hip/hip_runtime.h>

typedef _Float16 f16;
typedef _Float16 f16x8 __attribute__((ext_vector_type(8)));
typedef float f32x4 __attribute__((ext_vector_type(4)));

#define LN4 1.3862943611198906f

__device__ __forceinline__ void gl_lds16(const void* g, void* l) {
    typedef unsigned int u32;
    __builtin_amdgcn_global_load_lds(
        (const __attribute__((address_space(1))) u32*)(g),
        (__attribute__((address_space(3))) u32*)(l), 16, 0, 0);
}

// ===========================================================================
// Level-1 weight prep: fp32 W1[27][80][80] -> f16 hi/lo transposed:
// WT[d][tap][ h(80) | l(80) ], d<80, tap<28 (tap 27 = zeros).
// ===========================================================================
__global__ __launch_bounds__(256) void prep_w1_kernel(
    const float* __restrict__ W, f16* __restrict__ dst)
{
    const int CIN = 80, COUT = 80;
    int total = COUT * 28 * CIN;
    for (int i = blockIdx.x * 256 + threadIdx.x; i < total; i += gridDim.x * 256) {
        int d = i / (28 * CIN);
        int rem = i - d * (28 * CIN);
        int tap = rem / CIN;
        int c = rem - tap * CIN;
        float v = (tap < 27) ? W[(size_t)(tap * CIN + c) * COUT + d] : 0.f;
        f16 h = (f16)v;
        size_t base = (size_t)d * (28 * 2 * CIN) + (size_t)tap * (2 * CIN);
        dst[base + c] = h;
        dst[base + CIN + c] = (f16)(v - (float)h);
    }
}

// ===========================================================================
// Score-weight fragment table for score_tile's B operand (R8-verified).
// FT[(p*KB+kb)][term(2)][lane(64)][8] f16. k = kb*32+(lane>>4)*8+j;
// ts=k>=CIN; tap=2p+ts; col=lane&15.
// ===========================================================================
template<int CIN, int COUT>
__global__ __launch_bounds__(256) void prep_frag(
    const float* __restrict__ Wa, int ca, f16* __restrict__ FT)
{
    constexpr int KB = (2 * CIN) / 32;
    int total = 14 * KB * 1024;
    for (int i = blockIdx.x * 256 + threadIdx.x; i < total; i += gridDim.x * 256) {
        int j = i & 7;
        int lane = (i >> 3) & 63;
        int term = (i >> 9) & 1;
        int kbp = i >> 10;
        int kb = kbp % KB, p = kbp / KB;
        int k = kb * 32 + ((lane >> 4) * 8) + j;
        int ts = (k >= CIN) ? 1 : 0;
        int kk = k - ts * CIN;
        int tap = 2 * p + ts;
        int col = lane & 15;
        float v = 0.f;
        if (tap < 27 && col < COUT && col < ca) {
            int kc = tap * CIN + kk;
            v = Wa[(size_t)kc * ca + col];
        }
        f16 h = (f16)v;
        FT[i] = term ? (f16)(v - (float)h) : h;
    }
}

// Level-1 feature split: rows [h(80)|l(80)] f16, zero-sentinel row at n==N.
__global__ __launch_bounds__(256) void split80_kernel(
    const float* __restrict__ f, f16* __restrict__ Fc, int N)
{
    int i = blockIdx.x * 256 + threadIdx.x;
    if (i >= (N + 1) * 80) return;
    int n = i / 80, c = i - n * 80;
    float v = (n < N) ? f[i] : 0.f;
    f16 h = (f16)v;
    Fc[(size_t)n * 160 + c] = h;
    Fc[(size_t)n * 160 + 80 + c] = (f16)(v - (float)h);
}

__global__ __launch_bounds__(256) void ppn_finalize_kernel(
    const int* __restrict__ coords, const float* __restrict__ s,
    float* __restrict__ ppn, float* __restrict__ mask, int N)
{
    int n = blockIdx.x * 256 + threadIdx.x;
    if (n >= N) return;
    float s0 = s[(size_t)n * 2 + 0], s1 = s[(size_t)n * 2 + 1];
    ppn[(size_t)n * 6 + 0] = (float)coords[(size_t)n * 4 + 0];
    ppn[(size_t)n * 6 + 1] = (float)coords[(size_t)n * 4 + 1];
    ppn[(size_t)n * 6 + 2] = (float)coords[(size_t)n * 4 + 2];
    ppn[(size_t)n * 6 + 3] = (float)coords[(size_t)n * 4 + 3];
    ppn[(size_t)n * 6 + 4] = s0;
    ppn[(size_t)n * 6 + 5] = s1;
    mask[n] = (s1 - s0 > LN4) ? 1.0f : 0.0f;
}

// act[i] = mask[parent[i]]
__global__ __launch_bounds__(256) void gate_kernel(
    const float* __restrict__ mask, const int* __restrict__ parent,
    float* __restrict__ act, int N)
{
    int i = blockIdx.x * 256 + threadIdx.x;
    if (i < N) act[i] = mask[parent[i]];
}

// flag[nbr[m][t]] = 1 for every active source m (nbr symmetry => exact
// "row n has >=1 active neighbor" indicator). FSRC: float src, else int src.
template<bool FSRC>
__global__ __launch_bounds__(256) void expand_kernel(
    const void* __restrict__ src, const int* __restrict__ nbr,
    int* __restrict__ flag, int N)
{
    int m = blockIdx.x * 256 + threadIdx.x;
    if (m >= N) return;
    bool a = FSRC ? (((const float*)src)[m] != 0.f) : (((const int*)src)[m] != 0);
    if (!a) return;
    #pragma unroll 1
    for (int t = 0; t < 27; ++t) {
        int idx = nbr[(size_t)m * 27 + t];
        if (idx < N) flag[idx] = 1;
    }
}

// wave-aggregated compaction: list[0..cnt) = rows with flag!=0
__global__ __launch_bounds__(256) void compact_kernel(
    const int* __restrict__ flag, int* __restrict__ list,
    int* __restrict__ cnt, int N)
{
    int i = blockIdx.x * 256 + threadIdx.x;
    int lane = threadIdx.x & 63;
    bool f = (i < N) && (flag[i] != 0);
    unsigned long long m = __ballot(f);
    int base = 0;
    if (lane == 0 && m) base = atomicAdd(cnt, __popcll(m));
    base = __shfl(base, 0);
    if (f) list[base + __popcll(m & ((1ull << lane) - 1ull))] = i;
}

// ===========================================================================
// Level 1: MFMA conv80 (f16-split, 3-term). R9: rule-#20 fix — phase loop
// unrolled by 2 with NAMED fragment buffers (all compile-time indices, no
// runtime `buf` -> fragments stay in VGPRs, no scratch). Epilogue stores
// y1 split-f16 coalesced (atomic scatter removed; score via score_tile).
// ===========================================================================
__global__ __launch_bounds__(256, 3) void conv80_y(
    const f16* __restrict__ F, const int* __restrict__ nbr,
    const f16* __restrict__ WT, f16* __restrict__ Y, int N, int nTiles)
{
    constexpr int RE = 160, CPT = 20, CPR = 40, PB = 640, KB = 5, BM = 64;
    __shared__ __align__(16) char BS[80 * PB];     // 51200 B

    const int t = threadIdx.x;
    const int lane = t & 63;
    const int l16 = lane & 15;
    const int quad = lane >> 4;
    const int wv = t >> 6;

    int q8 = (nTiles + 7) >> 3;
    int tile = (blockIdx.x & 7) * q8 + (blockIdx.x >> 3);
    if (tile >= nTiles) return;
    const int m0 = tile * BM;
    const int grow = m0 + wv * 16 + l16;

    f16x8 ahA[KB], alA[KB], ahB[KB], alB[KB];

    auto loadA = [&](int p, f16x8 (&ah)[KB], f16x8 (&al)[KB]) {
        int i0 = N, i1 = N;
        if (grow < N) {
            i0 = nbr[(size_t)grow * 27 + 2 * p];
            if (2 * p + 1 < 27) i1 = nbr[(size_t)grow * 27 + 2 * p + 1];
        }
        #pragma unroll
        for (int kb = 0; kb < KB; ++kb) {
            int ko = kb * 32 + quad * 8;
            int ts = ko >= 80;
            int c2 = ko - (ts ? 80 : 0);
            const f16* ap = F + (size_t)(ts ? i1 : i0) * RE + c2;
            ah[kb] = *(const f16x8*)ap;
            al[kb] = *(const f16x8*)(ap + 80);
        }
    };

    auto stageB = [&](int p) {
        for (int i = t; i < 80 * CPR; i += 256) {
            int d = i / CPR, cs = i - d * CPR;
            int c = (cs & ~7) | ((cs ^ d) & 7);
            int tp = c / CPT, cc = c - tp * CPT;
            gl_lds16((const char*)WT + (((size_t)d * 28 + 2 * p + tp) * RE + cc * 8) * 2,
                     BS + (size_t)i * 16);
        }
    };

    f32x4 acc[5];
    #pragma unroll
    for (int ct = 0; ct < 5; ++ct) acc[ct] = (f32x4){0.f, 0.f, 0.f, 0.f};

    auto compute = [&](f16x8 (&ah)[KB], f16x8 (&al)[KB]) {
        #pragma unroll
        for (int kb = 0; kb < KB; ++kb) {
            int ko = kb * 32 + quad * 8;
            int ts = ko >= 80;
            int c2 = ko - (ts ? 80 : 0);
            int ch = ts * CPT + c2 / 8;
            int chl = ch + 10;
            #pragma unroll
            for (int ct = 0; ct < 5; ++ct) {
                int drow = ct * 16 + l16;
                int sb = (ch & ~7) | ((ch ^ drow) & 7);
                int sbl = (chl & ~7) | ((chl ^ drow) & 7);
                f16x8 bh = *(const f16x8*)(BS + drow * PB + sb * 16);
                f16x8 bl = *(const f16x8*)(BS + drow * PB + sbl * 16);
                acc[ct] = __builtin_amdgcn_mfma_f32_16x16x32_f16(ah[kb], bh, acc[ct], 0, 0, 0);
                acc[ct] = __builtin_amdgcn_mfma_f32_16x16x32_f16(al[kb], bh, acc[ct], 0, 0, 0);
                acc[ct] = __builtin_amdgcn_mfma_f32_16x16x32_f16(ah[kb], bl, acc[ct], 0, 0, 0);
            }
        }
    };

    loadA(0, ahA, alA);
    #pragma unroll 1
    for (int p = 0; p < 14; p += 2) {
        __syncthreads();
        stageB(p);
        loadA(p + 1, ahB, alB);          // p+1 <= 13 always
        __syncthreads();
        compute(ahA, alA);

        __syncthreads();
        stageB(p + 1);
        if (p + 2 < 14) loadA(p + 2, ahA, alA);
        __syncthreads();
        compute(ahB, alB);
    }

    // split-store epilogue (coalesced 2B stores, no atomics) — R8-verified
    #pragma unroll
    for (int ct = 0; ct < 5; ++ct) {
        #pragma unroll
        for (int r = 0; r < 4; ++r) {
            int row = m0 + wv * 16 + quad * 4 + r;
            if (row < N) {
                int d = ct * 16 + l16;
                float v = acc[ct][r];
                f16 h = (f16)v;
                Y[(size_t)row * RE + d] = h;
                Y[(size_t)row * RE + 80 + d] = (f16)(v - (float)h);
            }
        }
    }
}

// ===========================================================================
// Gather-form score conv (R8-verified): S[n] = sum_t Y[nbr[n][t]] @ Ws[t].
// MFMA, B from FT table. No LDS, no barriers, no atomics.
// ===========================================================================
template<int CIN, int COUT>
__global__ __launch_bounds__(256) void score_tile(
    const f16* __restrict__ Y, const int* __restrict__ nbr,
    const f16* __restrict__ FT, float* __restrict__ S, int N, int nTiles)
{
    constexpr int RE = 2 * CIN;
    constexpr int KB = RE / 32;

    const int t = threadIdx.x;
    const int lane = t & 63;
    const int l16 = lane & 15;
    const int quad = lane >> 4;
    const int wv = t >> 6;

    int q8 = (nTiles + 7) >> 3;
    int tile = (blockIdx.x & 7) * q8 + (blockIdx.x >> 3);
    if (tile >= nTiles) return;
    const int m0 = tile * 64;
    const int grow = m0 + wv * 16 + l16;
    const bool gv = grow < N;

    f32x4 acc = (f32x4){0.f, 0.f, 0.f, 0.f};

    #pragma unroll 1
    for (int p = 0; p < 14; ++p) {
        int i0 = N, i1 = N;
        if (gv) {
            i0 = nbr[(size_t)grow * 27 + 2 * p];
            if (2 * p + 1 < 27) i1 = nbr[(size_t)grow * 27 + 2 * p + 1];
        }
        #pragma unroll
        for (int kb = 0; kb < KB; ++kb) {
            int ko = kb * 32 + quad * 8;
            int ts = ko >= CIN;
            int c2 = ko - (ts ? CIN : 0);
            const f16* ap = Y + (size_t)(ts ? i1 : i0) * RE + c2;
            f16x8 ah = *(const f16x8*)ap;
            f16x8 al = *(const f16x8*)(ap + CIN);
            const f16* fb = FT + (size_t)(p * KB + kb) * 1024 + lane * 8;
            f16x8 bh = *(const f16x8*)fb;
            f16x8 bl = *(const f16x8*)(fb + 512);
            acc = __builtin_amdgcn_mfma_f32_16x16x32_f16(ah, bh, acc, 0, 0, 0);
            acc = __builtin_amdgcn_mfma_f32_16x16x32_f16(al, bh, acc, 0, 0, 0);
            acc = __builtin_amdgcn_mfma_f32_16x16x32_f16(ah, bl, acc, 0, 0, 0);
        }
    }

    if (l16 < COUT) {
        #pragma unroll
        for (int r = 0; r < 4; ++r) {
            int row = m0 + wv * 16 + quad * 4 + r;
            if (row < N) S[(size_t)row * COUT + l16] = acc[r];
        }
    }
}

// ===========================================================================
// Level 2 compute: persistent waves over compacted active-row list.
// (Round-0 measured version, unchanged.)
// ===========================================================================
__global__ __launch_bounds__(256) void lvl2_compute(
    const float* __restrict__ feat2, const int* __restrict__ nbr2,
    const float* __restrict__ act, const float* __restrict__ W2,
    const float* __restrict__ W2s, float* __restrict__ s2,
    const int* __restrict__ list, const int* __restrict__ cnt, int N)
{
    const int lane = threadIdx.x & 63;
    const int wid0 = (blockIdx.x * 256 + threadIdx.x) >> 6;
    const int nw = (gridDim.x * 256) >> 6;
    const int count = *cnt;
    const int c = lane;

    for (int w = wid0; w < count; w += nw) {
        const int n = list[w];
        int ld = N;
        if (lane < 27) ld = nbr2[(size_t)n * 27 + lane];
        bool valid = (lane < 27) && (ld < N);
        float a = valid ? act[ld] : 0.f;
        unsigned long long actm = __ballot(a != 0.f);
        unsigned long long vmask = __ballot(valid);

        float acc = 0.f;
        unsigned long long m = actm;
        while (m) {
            int t = __ffsll(m) - 1; m &= m - 1;
            int idx = __shfl(ld, t);
            const float4* f4 = (const float4*)(feat2 + (size_t)idx * 48);
            const float* wgt = W2 + (size_t)t * 48 * 48;
            #pragma unroll
            for (int q = 0; q < 12; ++q) {
                float4 fv = f4[q];                 // uniform address -> broadcast
                if (c < 48) {
                    acc += fv.x * wgt[(4 * q + 0) * 48 + c];
                    acc += fv.y * wgt[(4 * q + 1) * 48 + c];
                    acc += fv.z * wgt[(4 * q + 2) * 48 + c];
                    acc += fv.w * wgt[(4 * q + 3) * 48 + c];
                }
            }
        }

        m = vmask;
        while (m) {
            int t = __ffsll(m) - 1; m &= m - 1;
            int idx = __shfl(ld, t);
            float p0 = 0.f, p1 = 0.f;
            if (c < 48) {
                float2 wv2 = ((const float2*)W2s)[(size_t)(26 - t) * 48 + c];
                p0 = acc * wv2.x; p1 = acc * wv2.y;
            }
            #pragma unroll
            for (int s = 32; s; s >>= 1) { p0 += __shfl_down(p0, s); p1 += __shfl_down(p1, s); }
            if (lane == 0) {
                atomicAdd(&s2[(size_t)idx * 2 + 0], p0);
                atomicAdd(&s2[(size_t)idx * 2 + 1], p1);
            }
        }
    }
}

// ===========================================================================
// Level 3 compute kernels over compacted lists (zbuf / points pre-zeroed).
// (Round-0 measured versions, unchanged.)
// ===========================================================================
__global__ __launch_bounds__(256) void lvl3_z_compute(
    const float* __restrict__ feat3, const int* __restrict__ nbr3,
    const float* __restrict__ act, const float* __restrict__ W3,
    float* __restrict__ z, const int* __restrict__ list,
    const int* __restrict__ cnt, int N)
{
    const int lane = threadIdx.x & 63;
    const int wid0 = (blockIdx.x * 256 + threadIdx.x) >> 6;
    const int nw = (gridDim.x * 256) >> 6;
    const int count = *cnt;
    const int c = lane;

    for (int w = wid0; w < count; w += nw) {
        const int n = list[w];
        int ld = N;
        if (lane < 27) ld = nbr3[(size_t)n * 27 + lane];
        bool valid = (lane < 27) && (ld < N);
        float a = valid ? act[ld] : 0.f;
        unsigned long long m = __ballot(a != 0.f);

        float acc = 0.f;
        while (m) {
            int t = __ffsll(m) - 1; m &= m - 1;
            int idx = __shfl(ld, t);
            const float4* f4 = (const float4*)(feat3 + (size_t)idx * 16);
            const float* wgt = W3 + (size_t)t * 256;
            #pragma unroll
            for (int q = 0; q < 4; ++q) {
                float4 fv = f4[q];
                if (c < 16) {
                    acc += fv.x * wgt[(4 * q + 0) * 16 + c];
                    acc += fv.y * wgt[(4 * q + 1) * 16 + c];
                    acc += fv.z * wgt[(4 * q + 2) * 16 + c];
                    acc += fv.w * wgt[(4 * q + 3) * 16 + c];
                }
            }
        }
        if (lane < 16) z[(size_t)n * 16 + lane] = acc;
    }
}

__global__ __launch_bounds__(256) void lvl3_pts_compute(
    const float* __restrict__ z, const int* __restrict__ zflag,
    const int* __restrict__ nbr3,
    const float* __restrict__ Wp, const float* __restrict__ Ws,
    const float* __restrict__ Wt, float* __restrict__ points,
    const int* __restrict__ list, const int* __restrict__ cnt, int N)
{
    const int lane = threadIdx.x & 63;
    const int wid0 = (blockIdx.x * 256 + threadIdx.x) >> 6;
    const int nw = (gridDim.x * 256) >> 6;
    const int count = *cnt;
    const int c = lane;

    for (int w = wid0; w < count; w += nw) {
        const int n = list[w];
        int ld = N;
        if (lane < 27) ld = nbr3[(size_t)n * 27 + lane];
        bool valid = (lane < 27) && (ld < N);
        int zf = valid ? zflag[ld] : 0;
        unsigned long long m = __ballot(zf != 0);

        float acc = 0.f;
        while (m) {
            int t = __ffsll(m) - 1; m &= m - 1;
            int idx = __shfl(ld, t);
            const float4* z4 = (const float4*)(z + (size_t)idx * 16);
            #pragma unroll
            for (int q = 0; q < 4; ++q) {
                float4 zv = z4[q];
                if (c < 10) {
                    #pragma unroll
                    for (int j = 0; j < 4; ++j) {
                        int k = 4 * q + j;
                        int kc = t * 16 + k;
                        float wv = (c < 3) ? Wp[(size_t)kc * 3 + c]
                                 : (c < 5) ? Ws[(size_t)kc * 2 + (c - 3)]
                                           : Wt[(size_t)kc * 5 + (c - 5)];
                        float zj = (j == 0) ? zv.x : (j == 1) ? zv.y : (j == 2) ? zv.z : zv.w;
                        acc += zj * wv;
                    }
                }
            }
        }
        if (lane < 10) points[(size_t)n * 10 + lane] = acc;
    }
}

// ===========================================================================
extern "C" void kernel_launch(void* const* d_in, const int* in_sizes, int n_in,
                              void* d_out, int out_size, void* d_ws, size_t ws_size,
                              hipStream_t stream)
{
    const float* feat1 = (const float*)d_in[0];
    const float* feat2 = (const float*)d_in[1];
    const float* feat3 = (const float*)d_in[2];
    const float* W1    = (const float*)d_in[3];
    const float* W1s   = (const float*)d_in[4];
    const float* W2    = (const float*)d_in[5];
    const float* W2s   = (const float*)d_in[6];
    const float* W3    = (const float*)d_in[7];
    const float* W3p   = (const float*)d_in[8];
    const float* W3s   = (const float*)d_in[9];
    const float* W3t   = (const float*)d_in[10];
    const int* nbr1    = (const int*)d_in[11];
    const int* nbr2    = (const int*)d_in[12];
    const int* nbr3    = (const int*)d_in[13];
    const int* parent2 = (const int*)d_in[14];
    const int* parent3 = (const int*)d_in[15];
    const int* coords1 = (const int*)d_in[16];
    const int* coords2 = (const int*)d_in[17];

    const int N1 = in_sizes[0] / 80;
    const int N2 = in_sizes[1] / 48;
    const int N3 = in_sizes[2] / 16;

    float* out = (float*)d_out;
    float* o_points = out;                              // [N3,10]
    float* o_ppn1   = o_points + (size_t)N3 * 10;       // [N1,6]
    float* o_ppn2   = o_ppn1 + (size_t)N1 * 6;          // [N2,6]
    float* o_mask1  = o_ppn2 + (size_t)N2 * 6;          // [N1]
    float* o_mask2  = o_mask1 + (size_t)N1;             // [N2]

    char* wp = (char*)d_ws;
    auto alloc = [&](size_t bytes) -> char* {
        char* r = wp; wp += (bytes + 255) & ~(size_t)255; return r;
    };
    f16*   WT1   = (f16*)alloc((size_t)80 * 28 * 160 * 2);
    f16*   FT1   = (f16*)alloc((size_t)14 * 5 * 1024 * 2);
    f16*   Fa    = (f16*)alloc((size_t)(N1 + 1) * 160 * 2);
    f16*   Y1    = (f16*)alloc((size_t)(N1 + 1) * 160 * 2);
    float* s1    = (float*)alloc((size_t)(N1 + 1) * 2 * 4);
    float* s2    = (float*)alloc((size_t)(N2 + 1) * 2 * 4);
    float* act2  = (float*)alloc((size_t)N2 * 4);
    float* act3  = (float*)alloc((size_t)N3 * 4);
    int*   flag2 = (int*)alloc((size_t)N2 * 4);
    int*   list2 = (int*)alloc((size_t)N2 * 4);
    int*   flagz = (int*)alloc((size_t)N3 * 4);
    int*   listz = (int*)alloc((size_t)N3 * 4);
    int*   flagp = (int*)alloc((size_t)N3 * 4);
    int*   listp = (int*)alloc((size_t)N3 * 4);
    float* zbuf  = (float*)alloc((size_t)N3 * 16 * 4);
    int*   cnts  = (int*)alloc(3 * 4);    // [cnt2, cntz, cntp]

    auto cdiv = [](long long a, long long b) { return (int)((a + b - 1) / b); };

    // zero the accumulators / flags / counters / zero-default outputs
    hipMemsetAsync(s1, 0, (size_t)(N1 + 1) * 2 * 4, stream);
    hipMemsetAsync(s2, 0, (size_t)(N2 + 1) * 2 * 4, stream);
    hipMemsetAsync(Y1 + (size_t)N1 * 160, 0, 160 * 2, stream);  // zero sentinel row
    hipMemsetAsync(flag2, 0, (size_t)N2 * 4, stream);
    hipMemsetAsync(flagz, 0, (size_t)N3 * 4, stream);
    hipMemsetAsync(flagp, 0, (size_t)N3 * 4, stream);
    hipMemsetAsync(zbuf, 0, (size_t)N3 * 16 * 4, stream);
    hipMemsetAsync(cnts, 0, 3 * 4, stream);
    hipMemsetAsync(o_points, 0, (size_t)N3 * 10 * 4, stream);

    // ---- level 1: dense MFMA conv80 -> y1, then atomic-free score tile ----
    prep_w1_kernel<<<700, 256, 0, stream>>>(W1, WT1);
    prep_frag<80, 2><<<cdiv(14 * 5 * 1024, 256), 256, 0, stream>>>(W1s, 2, FT1);
    split80_kernel<<<cdiv((size_t)(N1 + 1) * 80, 256), 256, 0, stream>>>(feat1, Fa, N1);
    {
        int T = cdiv(N1, 64);
        dim3 grid(8 * cdiv(T, 8));
        conv80_y<<<grid, 256, 0, stream>>>(Fa, nbr1, WT1, Y1, N1, T);
        score_tile<80, 2><<<grid, 256, 0, stream>>>(Y1, nbr1, FT1, s1, N1, T);
    }
    ppn_finalize_kernel<<<cdiv(N1, 256), 256, 0, stream>>>(coords1, s1, o_ppn1, o_mask1, N1);

    // ---- level 2: expand -> compact -> persistent sparse compute ----
    gate_kernel<<<cdiv(N2, 256), 256, 0, stream>>>(o_mask1, parent2, act2, N2);
    expand_kernel<true><<<cdiv(N2, 256), 256, 0, stream>>>(act2, nbr2, flag2, N2);
    compact_kernel<<<cdiv(N2, 256), 256, 0, stream>>>(flag2, list2, &cnts[0], N2);
    lvl2_compute<<<2048, 256, 0, stream>>>(feat2, nbr2, act2, W2, W2s, s2,
                                           list2, &cnts[0], N2);
    ppn_finalize_kernel<<<cdiv(N2, 256), 256, 0, stream>>>(coords2, s2, o_ppn2, o_mask2, N2);

    // ---- level 3: two-hop expand/compact, z then points ----
    gate_kernel<<<cdiv(N3, 256), 256, 0, stream>>>(o_mask2, parent3, act3, N3);
    expand_kernel<true><<<cdiv(N3, 256), 256, 0, stream>>>(act3, nbr3, flagz, N3);
    compact_kernel<<<cdiv(N3, 256), 256, 0, stream>>>(flagz, listz, &cnts[1], N3);
    lvl3_z_compute<<<2048, 256, 0, stream>>>(feat3, nbr3, act3, W3, zbuf,
                                             listz, &cnts[1], N3);
    expand_kernel<false><<<cdiv(N3, 256), 256, 0, stream>>>(flagz, nbr3, flagp, N3);
    compact_kernel<<<cdiv(N3, 256), 256, 0, stream>>>(flagp, listp, &cnts[2], N3);
    lvl3_pts_compute<<<2048, 256, 0, stream>>>(zbuf, flagz, nbr3, W3p, W3s, W3t,
                                               o_points, listp, &cnts[2], N3);
}